// Round 6
// baseline (227.911 us; speedup 1.0000x reference)
//
#include <hip/hip_runtime.h>
#include <hip/hip_bf16.h>
#include <math.h>

typedef float f32x4 __attribute__((ext_vector_type(4)));
typedef __bf16 bf16x8 __attribute__((ext_vector_type(8)));
typedef unsigned short u16;
typedef u16 u16x8 __attribute__((ext_vector_type(8)));
typedef u16 u16x4 __attribute__((ext_vector_type(4)));

// round-to-nearest-even fp32 -> bf16
__device__ __forceinline__ u16 f2bf(float f) {
    unsigned u = __builtin_bit_cast(unsigned, f);
    u = (u + 0x7fffu + ((u >> 16) & 1u)) >> 16;
    return (u16)u;
}
// pack two fp32 -> two bf16 (round-half-up) in one v_perm: (hi16(b)<<16)|hi16(a)
__device__ __forceinline__ unsigned pack2_rhu(float a, float b) {
    return __builtin_amdgcn_perm(__builtin_bit_cast(unsigned, b) + 0x8000u,
                                 __builtin_bit_cast(unsigned, a) + 0x8000u,
                                 0x07060302u);
}

#if __has_builtin(__builtin_amdgcn_exp2f)
#define EXP2(x) __builtin_amdgcn_exp2f(x)
#else
#define EXP2(x) exp2f(x)
#endif

// async global->LDS 16B/lane: LDS dest = wave-uniform base + lane*16
__device__ __forceinline__ void gload16(const u16* g, u16* l) {
    __builtin_amdgcn_global_load_lds(
        (const __attribute__((address_space(1))) unsigned int*)(g),
        (__attribute__((address_space(3))) unsigned int*)(l), 16, 0, 0);
}

// ---------------- fused cast fp32 -> bf16 for all 7 inputs ----------------
__global__ __launch_bounds__(256) void cast_all(
    const float* __restrict__ q, const float* __restrict__ k, const float* __restrict__ v,
    const float* __restrict__ wq, const float* __restrict__ wk, const float* __restrict__ wv,
    const float* __restrict__ wo, u16* __restrict__ dst) {
    int i = blockIdx.x * 256 + threadIdx.x;  // float4 index, grid covers 4194304 exactly
    const float* src;
    int off;
    if (i < 3145728) {
        int seg = i >> 20;
        src = (seg == 0) ? q : (seg == 1) ? k : v;
        off = i - (seg << 20);
    } else {
        int j = (i - 3145728) >> 18;
        src = (j == 0) ? wq : (j == 1) ? wk : (j == 2) ? wv : wo;
        off = (i - 3145728) - (j << 18);
    }
    float4 val = ((const float4*)src)[off];
    u16x4 o4;
    o4.x = f2bf(val.x); o4.y = f2bf(val.y); o4.z = f2bf(val.z); o4.w = f2bf(val.w);
    ((u16x4*)dst)[i] = o4;
}

// ---------------- fused QKV projection GEMM (async-LDS, XOR-swizzled) ----------------
// C = X @ W.T, M=4096, N=1024, K=1024. Tile 128x128, BK=64.
// NOTE: no min-waves hint — unified VGPR/AGPR file; capping waves forced acc spills
// to scratch = 305 MB of HBM write traffic (round-4 bug).
// z=0: Q -> [B,H,S,D] scaled by 0.125*log2(e); z=1: K -> [B,H,S,D]; z=2: V -> [B,H,D,S]
__global__ __launch_bounds__(256) void qkv_gemm(
    const u16* __restrict__ Xq, const u16* __restrict__ Xk, const u16* __restrict__ Xv,
    const u16* __restrict__ Wq, const u16* __restrict__ Wk, const u16* __restrict__ Wv,
    u16* __restrict__ Qo, u16* __restrict__ Ko, u16* __restrict__ Vto) {
    constexpr int K = 1024;
    const int z = blockIdx.z;
    const u16* __restrict__ A = (z == 0) ? Xq : (z == 1) ? Xk : Xv;
    const u16* __restrict__ W = (z == 0) ? Wq : (z == 1) ? Wk : Wv;
    u16* __restrict__ Out = (z == 0) ? Qo : (z == 1) ? Ko : Vto;

    __shared__ __align__(16) u16 As[128 * 64];  // 16 KB
    __shared__ __align__(16) u16 Bs[128 * 64];  // 16 KB

    const int t = threadIdx.x;
    const int lane = t & 63, wave = t >> 6;
    const int quad = lane >> 4, c = lane & 15, cx = c & 7;
    const int wr = (wave >> 1) * 64, wc = (wave & 1) * 64;
    const int rowA0 = blockIdx.y * 128;
    const int colB0 = blockIdx.x * 128;

    const int l3 = lane >> 3, l7 = lane & 7;
    const int chs = (l7 ^ l3) << 3;
    const u16* gA[4];
    const u16* gB[4];
    u16* lA[4];
    u16* lB[4];
#pragma unroll
    for (int i = 0; i < 4; ++i) {
        int row = wave * 32 + i * 8 + l3;
        gA[i] = A + (size_t)(rowA0 + row) * K + chs;
        gB[i] = W + (size_t)(colB0 + row) * K + chs;
        lA[i] = As + (wave * 256 + i * 64) * 8;
        lB[i] = Bs + (wave * 256 + i * 64) * 8;
    }

    const f32x4 zero4 = {0.f, 0.f, 0.f, 0.f};
    f32x4 acc[4][4];
#pragma unroll
    for (int i = 0; i < 4; ++i)
#pragma unroll
        for (int j = 0; j < 4; ++j) acc[i][j] = zero4;

    for (int kt = 0; kt < K; kt += 64) {
        __syncthreads();  // prior tile's reads complete
#pragma unroll
        for (int i = 0; i < 4; ++i) {
            gload16(gA[i] + kt, lA[i]);
            gload16(gB[i] + kt, lB[i]);
        }
        __syncthreads();  // staged data visible (vmcnt drained by barrier)
#pragma unroll
        for (int ks = 0; ks < 2; ++ks) {
            const int co = ((ks * 4 + quad) ^ cx) << 3;
            bf16x8 af[4], bfr[4];
#pragma unroll
            for (int i = 0; i < 4; ++i)
                af[i] = *(const bf16x8*)(As + (wr + i * 16 + c) * 64 + co);
#pragma unroll
            for (int j = 0; j < 4; ++j)
                bfr[j] = *(const bf16x8*)(Bs + (wc + j * 16 + c) * 64 + co);
            if (z == 2) {
#pragma unroll
                for (int i = 0; i < 4; ++i)
#pragma unroll
                    for (int j = 0; j < 4; ++j)
                        acc[i][j] = __builtin_amdgcn_mfma_f32_16x16x32_bf16(bfr[j], af[i], acc[i][j], 0, 0, 0);
            } else {
#pragma unroll
                for (int i = 0; i < 4; ++i)
#pragma unroll
                    for (int j = 0; j < 4; ++j)
                        acc[i][j] = __builtin_amdgcn_mfma_f32_16x16x32_bf16(af[i], bfr[j], acc[i][j], 0, 0, 0);
            }
        }
    }

    // 0.125 * log2(e): scores later exponentiate via exp2
    const float scale = (z == 0) ? 0.18033688011112042f : 1.0f;
#pragma unroll
    for (int i = 0; i < 4; ++i) {
#pragma unroll
        for (int j = 0; j < 4; ++j) {
#pragma unroll
            for (int r = 0; r < 4; ++r) {
                float v = acc[i][j][r];
                if (z == 2) {
                    int n = colB0 + wc + j * 16 + quad * 4 + r;  // feature (h*64+d)
                    int m = rowA0 + wr + i * 16 + c;             // token (b*2048+s)
                    int b = m >> 11, s = m & 2047, h = n >> 6, d = n & 63;
                    Out[((((b << 4) | h) << 6) + d) * 2048 + s] = f2bf(v);
                } else {
                    int m = rowA0 + wr + i * 16 + quad * 4 + r;  // token
                    int n = colB0 + wc + j * 16 + c;             // feature
                    int b = m >> 11, s = m & 2047, h = n >> 6, d = n & 63;
                    Out[((((b << 4) | h) * 2048 + s) << 6) + d] = f2bf(v * scale);
                }
            }
        }
    }
}

// ---------------- output projection GEMM (fp32 out, async-LDS, swizzled) ----------------
// Tile 64(M) x 128(N), grid (8, 64) = 512 blocks -> 2 blocks/CU.
// (256,2) is safe here: acc is only 32 AGPRs, cap at 2 waves/SIMD = 256 regs.
__global__ __launch_bounds__(256, 2) void out_gemm(const u16* __restrict__ A,
                                                   const u16* __restrict__ W,
                                                   float* __restrict__ Out) {
    constexpr int K = 1024;
    __shared__ __align__(16) u16 As[64 * 64];   // 8 KB
    __shared__ __align__(16) u16 Bs[128 * 64];  // 16 KB
    const int t = threadIdx.x;
    const int lane = t & 63, wave = t >> 6;
    const int quad = lane >> 4, c = lane & 15, cx = c & 7;
    const int wr = (wave >> 1) * 32, wc = (wave & 1) * 64;
    const int rowA0 = blockIdx.y * 64;
    const int colB0 = blockIdx.x * 128;

    const int l3 = lane >> 3, l7 = lane & 7;
    const int chs = (l7 ^ l3) << 3;
    const u16* gA[2];
    const u16* gB[4];
    u16* lA[2];
    u16* lB[4];
#pragma unroll
    for (int i = 0; i < 2; ++i) {
        int row = wave * 16 + i * 8 + l3;
        gA[i] = A + (size_t)(rowA0 + row) * K + chs;
        lA[i] = As + (wave * 128 + i * 64) * 8;
    }
#pragma unroll
    for (int i = 0; i < 4; ++i) {
        int row = wave * 32 + i * 8 + l3;
        gB[i] = W + (size_t)(colB0 + row) * K + chs;
        lB[i] = Bs + (wave * 256 + i * 64) * 8;
    }

    const f32x4 zero4 = {0.f, 0.f, 0.f, 0.f};
    f32x4 acc[2][4];
#pragma unroll
    for (int i = 0; i < 2; ++i)
#pragma unroll
        for (int j = 0; j < 4; ++j) acc[i][j] = zero4;

    for (int kt = 0; kt < K; kt += 64) {
        __syncthreads();
#pragma unroll
        for (int i = 0; i < 2; ++i) gload16(gA[i] + kt, lA[i]);
#pragma unroll
        for (int i = 0; i < 4; ++i) gload16(gB[i] + kt, lB[i]);
        __syncthreads();
#pragma unroll
        for (int ks = 0; ks < 2; ++ks) {
            const int co = ((ks * 4 + quad) ^ cx) << 3;
            bf16x8 af[2], bfr[4];
#pragma unroll
            for (int i = 0; i < 2; ++i)
                af[i] = *(const bf16x8*)(As + (wr + i * 16 + c) * 64 + co);
#pragma unroll
            for (int j = 0; j < 4; ++j)
                bfr[j] = *(const bf16x8*)(Bs + (wc + j * 16 + c) * 64 + co);
#pragma unroll
            for (int i = 0; i < 2; ++i)
#pragma unroll
                for (int j = 0; j < 4; ++j)
                    acc[i][j] = __builtin_amdgcn_mfma_f32_16x16x32_bf16(af[i], bfr[j], acc[i][j], 0, 0, 0);
        }
    }
#pragma unroll
    for (int i = 0; i < 2; ++i)
#pragma unroll
        for (int j = 0; j < 4; ++j)
#pragma unroll
            for (int r = 0; r < 4; ++r) {
                int m = rowA0 + wr + i * 16 + quad * 4 + r;
                int n = colB0 + wc + j * 16 + c;
                Out[(m << 10) + n] = acc[i][j][r];
            }
}

// ---------------- flash attention v5: software-skewed pipeline ----------------
// Iter t computes QK(t)+exp(t)+P-write(t) AND PV(t-1): PV(t-1) is independent of
// this iter's exp chain, so MFMA overlaps VALU. K double-buffered, V TRIPLE-
// buffered (consumed one iter after its staging window), P per-wave double-
// buffered. One barrier per iter; its lgkm-drain publishes P(t) for iter t+1 —
// no explicit lgkmcnt fence in the loop. LDS = 16+24+32 = 72 KB -> 2 blocks/CU.
__global__ __launch_bounds__(256) void flash_attn(const u16* __restrict__ Qp,
                                                  const u16* __restrict__ Kp,
                                                  const u16* __restrict__ Vt,
                                                  u16* __restrict__ Ob) {
    constexpr int S = 2048;
    constexpr int NT = S / 64;
    const int bh = blockIdx.y;
    const int b = bh >> 4, h = bh & 15;
    const int t = threadIdx.x, wave = t >> 6, lane = t & 63;
    const int quad = lane >> 4, c = lane & 15, cx = c & 7;
    const int qw = blockIdx.x * 128 + wave * 32;
    const u16* Qb = Qp + (bh * S + qw) * 64;
    const u16* Kb = Kp + (bh * S) * 64;
    const u16* Vb = Vt + bh * 64 * S;

    __shared__ __align__(16) u16 Ks[2][64 * 64];     // [key][dim], swizzled chunks
    __shared__ __align__(16) u16 Vs[3][64 * 64];     // [dim][key], swizzled chunks
    __shared__ __align__(16) u16 Ps[4][2][32 * 64];  // per-wave P dbuf [q][key], swizzled

    // Q fragments (B-operand): lane c holds Q[q=qt*16+c][dim=hf*32+quad*8+j]
    bf16x8 qf[2][2];
#pragma unroll
    for (int qt = 0; qt < 2; ++qt)
#pragma unroll
        for (int hf = 0; hf < 2; ++hf)
            qf[qt][hf] = *(const bf16x8*)(Qb + (qt * 16 + c) * 64 + hf * 32 + quad * 8);

    // staging: wave w instr i covers physical chunks [w*128+i*64, +64)
    const int l3 = lane >> 3, l7 = lane & 7;
    const int chs = (l7 ^ l3) << 3;
    const u16* gK[2];
    const u16* gV[2];
    int lbase[2];
#pragma unroll
    for (int i = 0; i < 2; ++i) {
        int row = wave * 16 + i * 8 + l3;
        gK[i] = Kb + row * 64 + chs;    // += kv*64 per tile
        gV[i] = Vb + row * 2048 + chs;  // += kv per tile
        lbase[i] = (wave * 128 + i * 64) * 8;
    }
    // preload tile 0
#pragma unroll
    for (int i = 0; i < 2; ++i) {
        gload16(gK[i], &Ks[0][lbase[i]]);
        gload16(gV[i], &Vs[0][lbase[i]]);
    }
    __syncthreads();

    const f32x4 zero4 = {0.f, 0.f, 0.f, 0.f};
    f32x4 o[2][4];
#pragma unroll
    for (int qt = 0; qt < 2; ++qt)
#pragma unroll
        for (int t2 = 0; t2 < 4; ++t2) o[qt][t2] = zero4;
    float lsum[2] = {0.f, 0.f};

    const int co0 = (quad ^ cx) << 3, co1 = ((4 + quad) ^ cx) << 3;
    int vb_prev = 2, vb_cur = 0, vb_next = 1;  // V(t-1), V(t), V(t+1) buffers

    for (int it = 0; it < NT; ++it) {
        // prefetch tile t+1 (drained by this iter's end barrier)
        if (it + 1 < NT) {
#pragma unroll
            for (int i = 0; i < 2; ++i) {
                gload16(gK[i] + (it + 1) * 4096, &Ks[(it + 1) & 1][lbase[i]]);
                gload16(gV[i] + (it + 1) * 64, &Vs[vb_next][lbase[i]]);
            }
        }
        // ---- QK(t): transposed scores Sc^T[key][q] = K_tile * Q^T ----
        const u16* Kc = &Ks[it & 1][0];
        f32x4 sc[4][2];
#pragma unroll
        for (int kt = 0; kt < 4; ++kt) {
            const int krow = (kt * 16 + c) * 64;
            bf16x8 kf0 = *(const bf16x8*)(Kc + krow + co0);
            bf16x8 kf1 = *(const bf16x8*)(Kc + krow + co1);
#pragma unroll
            for (int qt = 0; qt < 2; ++qt) {
                f32x4 zz = zero4;
                zz = __builtin_amdgcn_mfma_f32_16x16x32_bf16(kf0, qf[qt][0], zz, 0, 0, 0);
                zz = __builtin_amdgcn_mfma_f32_16x16x32_bf16(kf1, qf[qt][1], zz, 0, 0, 0);
                sc[kt][qt] = zz;
            }
        }
        // ---- PV(t-1): independent of QK(t)/exp(t) -> overlaps the exp chain ----
        if (it > 0) {
            const u16* Pwp = &Ps[wave][(it - 1) & 1][0];
            const u16* Vc = &Vs[vb_prev][0];
            bf16x8 pf[2][2];
#pragma unroll
            for (int qt = 0; qt < 2; ++qt) {
                pf[qt][0] = *(const bf16x8*)(Pwp + (qt * 16 + c) * 64 + co0);
                pf[qt][1] = *(const bf16x8*)(Pwp + (qt * 16 + c) * 64 + co1);
            }
#pragma unroll
            for (int t2 = 0; t2 < 4; ++t2) {
                const int vrow = (t2 * 16 + c) * 64;
                bf16x8 vf0 = *(const bf16x8*)(Vc + vrow + co0);
                bf16x8 vf1 = *(const bf16x8*)(Vc + vrow + co1);
#pragma unroll
                for (int qt = 0; qt < 2; ++qt) {
                    o[qt][t2] = __builtin_amdgcn_mfma_f32_16x16x32_bf16(pf[qt][0], vf0, o[qt][t2], 0, 0, 0);
                    o[qt][t2] = __builtin_amdgcn_mfma_f32_16x16x32_bf16(pf[qt][1], vf1, o[qt][t2], 0, 0, 0);
                }
            }
        }
        // ---- exp2 + pack + swizzled P(t) write (published by the barrier) ----
        // lane holds keys kt*16+quad*4+r for q = qt*16+c
        u16* Pwc = &Ps[wave][it & 1][0];
#pragma unroll
        for (int kt = 0; kt < 4; ++kt) {
            const int pchunk = ((kt * 2 + (quad >> 1)) ^ cx) << 3;
#pragma unroll
            for (int qt = 0; qt < 2; ++qt) {
                float p0 = EXP2(sc[kt][qt][0]);
                float p1 = EXP2(sc[kt][qt][1]);
                float p2 = EXP2(sc[kt][qt][2]);
                float p3 = EXP2(sc[kt][qt][3]);
                lsum[qt] += (p0 + p1) + (p2 + p3);
                uint2 pk;
                pk.x = pack2_rhu(p0, p1);
                pk.y = pack2_rhu(p2, p3);
                *(uint2*)(Pwc + (qt * 16 + c) * 64 + pchunk + (quad & 1) * 4) = pk;
            }
        }
        __syncthreads();  // buffer lifecycle + P publish + prefetch vmcnt drain
        int tmp = vb_prev;
        vb_prev = vb_cur;
        vb_cur = vb_next;
        vb_next = tmp;
    }
    // ---- final PV(NT-1) ----
    {
        const u16* Pwp = &Ps[wave][(NT - 1) & 1][0];
        const u16* Vc = &Vs[vb_prev][0];
        bf16x8 pf[2][2];
#pragma unroll
        for (int qt = 0; qt < 2; ++qt) {
            pf[qt][0] = *(const bf16x8*)(Pwp + (qt * 16 + c) * 64 + co0);
            pf[qt][1] = *(const bf16x8*)(Pwp + (qt * 16 + c) * 64 + co1);
        }
#pragma unroll
        for (int t2 = 0; t2 < 4; ++t2) {
            const int vrow = (t2 * 16 + c) * 64;
            bf16x8 vf0 = *(const bf16x8*)(Vc + vrow + co0);
            bf16x8 vf1 = *(const bf16x8*)(Vc + vrow + co1);
#pragma unroll
            for (int qt = 0; qt < 2; ++qt) {
                o[qt][t2] = __builtin_amdgcn_mfma_f32_16x16x32_bf16(pf[qt][0], vf0, o[qt][t2], 0, 0, 0);
                o[qt][t2] = __builtin_amdgcn_mfma_f32_16x16x32_bf16(pf[qt][1], vf1, o[qt][t2], 0, 0, 0);
            }
        }
    }
    // ---- reduce row-sums across quads; lane (c,quad) holds partial for q=qt*16+c ----
#pragma unroll
    for (int qt = 0; qt < 2; ++qt) {
        lsum[qt] += __shfl_xor(lsum[qt], 16);
        lsum[qt] += __shfl_xor(lsum[qt], 32);
    }
    // ---- epilogue: normalize and store [B,S,H,D] ----
#pragma unroll
    for (int qt = 0; qt < 2; ++qt)
#pragma unroll
        for (int r = 0; r < 4; ++r) {
            float inv = 1.f / __shfl(lsum[qt], quad * 4 + r);
            int row = qw + qt * 16 + quad * 4 + r;
            int base = ((b * S + row) * 16 + h) * 64;
#pragma unroll
            for (int t2 = 0; t2 < 4; ++t2)
                Ob[base + t2 * 16 + c] = f2bf(o[qt][t2][r] * inv);
        }
}

extern "C" void kernel_launch(void* const* d_in, const int* in_sizes, int n_in,
                              void* d_out, int out_size, void* d_ws, size_t ws_size,
                              hipStream_t stream) {
    const float* q  = (const float*)d_in[0];
    const float* k  = (const float*)d_in[1];
    const float* v  = (const float*)d_in[2];
    const float* wq = (const float*)d_in[3];
    const float* wk = (const float*)d_in[4];
    const float* wv = (const float*)d_in[5];
    const float* wo = (const float*)d_in[6];

    u16* ws = (u16*)d_ws;
    u16* qb  = ws;              // 4194304 elems
    u16* kb  = ws + 4194304;
    u16* vb  = ws + 8388608;
    u16* wqb = ws + 12582912;   // 1048576 elems each
    u16* wkb = ws + 13631488;
    u16* wvb = ws + 14680064;
    u16* wob = ws + 15728640;
    u16* Qp  = ws + 16777216;   // [B,H,S,D]
    u16* Kp  = ws + 20971520;   // [B,H,S,D]
    u16* Vtp = ws + 25165824;   // [B,H,D,S]
    u16* Obf = ws + 29360128;   // [B,S,H,D]

    cast_all<<<16384, 256, 0, stream>>>(q, k, v, wq, wk, wv, wo, ws);

    // fused QKV projections: grid (N/128, M/128, 3)
    qkv_gemm<<<dim3(8, 32, 3), 256, 0, stream>>>(qb, kb, vb, wqb, wkb, wvb, Qp, Kp, Vtp);

    // flash attention: grid (S/128, B*H), 4 waves per block
    flash_attn<<<dim3(16, 32), 256, 0, stream>>>(Qp, Kp, Vtp, Obf);

    // output projection: tile 64x128, grid (N/128, M/64)
    out_gemm<<<dim3(8, 64), 256, 0, stream>>>(Obf, wob, (float*)d_out);
}

// Round 7
// 214.191 us; speedup vs baseline: 1.0641x; 1.0641x over previous
//
#include <hip/hip_runtime.h>
#include <hip/hip_bf16.h>
#include <math.h>

typedef float f32x4 __attribute__((ext_vector_type(4)));
typedef __bf16 bf16x8 __attribute__((ext_vector_type(8)));
typedef unsigned short u16;
typedef u16 u16x8 __attribute__((ext_vector_type(8)));
typedef u16 u16x4 __attribute__((ext_vector_type(4)));

// round-to-nearest-even fp32 -> bf16
__device__ __forceinline__ u16 f2bf(float f) {
    unsigned u = __builtin_bit_cast(unsigned, f);
    u = (u + 0x7fffu + ((u >> 16) & 1u)) >> 16;
    return (u16)u;
}
// pack two fp32 -> two bf16 (round-half-up) in one v_perm: (hi16(b)<<16)|hi16(a)
__device__ __forceinline__ unsigned pack2_rhu(float a, float b) {
    return __builtin_amdgcn_perm(__builtin_bit_cast(unsigned, b) + 0x8000u,
                                 __builtin_bit_cast(unsigned, a) + 0x8000u,
                                 0x07060302u);
}

#if __has_builtin(__builtin_amdgcn_exp2f)
#define EXP2(x) __builtin_amdgcn_exp2f(x)
#else
#define EXP2(x) exp2f(x)
#endif

// async global->LDS 16B/lane: LDS dest = wave-uniform base + lane*16
__device__ __forceinline__ void gload16(const u16* g, u16* l) {
    __builtin_amdgcn_global_load_lds(
        (const __attribute__((address_space(1))) unsigned int*)(g),
        (__attribute__((address_space(3))) unsigned int*)(l), 16, 0, 0);
}

// ---------------- fused cast fp32 -> bf16 for all 7 inputs ----------------
__global__ __launch_bounds__(256) void cast_all(
    const float* __restrict__ q, const float* __restrict__ k, const float* __restrict__ v,
    const float* __restrict__ wq, const float* __restrict__ wk, const float* __restrict__ wv,
    const float* __restrict__ wo, u16* __restrict__ dst) {
    int i = blockIdx.x * 256 + threadIdx.x;  // float4 index, grid covers 4194304 exactly
    const float* src;
    int off;
    if (i < 3145728) {
        int seg = i >> 20;
        src = (seg == 0) ? q : (seg == 1) ? k : v;
        off = i - (seg << 20);
    } else {
        int j = (i - 3145728) >> 18;
        src = (j == 0) ? wq : (j == 1) ? wk : (j == 2) ? wv : wo;
        off = (i - 3145728) - (j << 18);
    }
    float4 val = ((const float4*)src)[off];
    u16x4 o4;
    o4.x = f2bf(val.x); o4.y = f2bf(val.y); o4.z = f2bf(val.z); o4.w = f2bf(val.w);
    ((u16x4*)dst)[i] = o4;
}

// ---------------- fused QKV projection GEMM (async-LDS, XOR-swizzled) ----------------
// C = X @ W.T, M=4096, N=1024, K=1024. Tile 128x128, BK=64. 1-D grid of 768:
// blk = x*96 + z*32 + y  =>  blk%8 == y%8, so the 8 x-tiles of a (z,y) group land
// on one XCD (block->XCD ~ blk%8): shared X-rows (0.5 MB) + W (2 MB) stay L2-resident.
// NOTE: no min-waves hint — unified VGPR/AGPR file; capping waves spilled acc to
// scratch = 305 MB of HBM writes (round-4 bug).
__global__ __launch_bounds__(256) void qkv_gemm(
    const u16* __restrict__ Xq, const u16* __restrict__ Xk, const u16* __restrict__ Xv,
    const u16* __restrict__ Wq, const u16* __restrict__ Wk, const u16* __restrict__ Wv,
    u16* __restrict__ Qo, u16* __restrict__ Ko, u16* __restrict__ Vto) {
    constexpr int K = 1024;
    const int blk = blockIdx.x;
    const int xb = blk / 96;
    const int zb = (blk % 96) >> 5;
    const int yb = blk & 31;
    const int z = zb;
    const u16* __restrict__ A = (z == 0) ? Xq : (z == 1) ? Xk : Xv;
    const u16* __restrict__ W = (z == 0) ? Wq : (z == 1) ? Wk : Wv;
    u16* __restrict__ Out = (z == 0) ? Qo : (z == 1) ? Ko : Vto;

    __shared__ __align__(16) u16 As[128 * 64];  // 16 KB
    __shared__ __align__(16) u16 Bs[128 * 64];  // 16 KB

    const int t = threadIdx.x;
    const int lane = t & 63, wave = t >> 6;
    const int quad = lane >> 4, c = lane & 15, cx = c & 7;
    const int wr = (wave >> 1) * 64, wc = (wave & 1) * 64;
    const int rowA0 = yb * 128;
    const int colB0 = xb * 128;

    const int l3 = lane >> 3, l7 = lane & 7;
    const int chs = (l7 ^ l3) << 3;
    const u16* gA[4];
    const u16* gB[4];
    u16* lA[4];
    u16* lB[4];
#pragma unroll
    for (int i = 0; i < 4; ++i) {
        int row = wave * 32 + i * 8 + l3;
        gA[i] = A + (size_t)(rowA0 + row) * K + chs;
        gB[i] = W + (size_t)(colB0 + row) * K + chs;
        lA[i] = As + (wave * 256 + i * 64) * 8;
        lB[i] = Bs + (wave * 256 + i * 64) * 8;
    }

    const f32x4 zero4 = {0.f, 0.f, 0.f, 0.f};
    f32x4 acc[4][4];
#pragma unroll
    for (int i = 0; i < 4; ++i)
#pragma unroll
        for (int j = 0; j < 4; ++j) acc[i][j] = zero4;

    for (int kt = 0; kt < K; kt += 64) {
        __syncthreads();  // prior tile's reads complete
#pragma unroll
        for (int i = 0; i < 4; ++i) {
            gload16(gA[i] + kt, lA[i]);
            gload16(gB[i] + kt, lB[i]);
        }
        __syncthreads();  // staged data visible (vmcnt drained by barrier)
#pragma unroll
        for (int ks = 0; ks < 2; ++ks) {
            const int co = ((ks * 4 + quad) ^ cx) << 3;
            bf16x8 af[4], bfr[4];
#pragma unroll
            for (int i = 0; i < 4; ++i)
                af[i] = *(const bf16x8*)(As + (wr + i * 16 + c) * 64 + co);
#pragma unroll
            for (int j = 0; j < 4; ++j)
                bfr[j] = *(const bf16x8*)(Bs + (wc + j * 16 + c) * 64 + co);
            if (z == 2) {
#pragma unroll
                for (int i = 0; i < 4; ++i)
#pragma unroll
                    for (int j = 0; j < 4; ++j)
                        acc[i][j] = __builtin_amdgcn_mfma_f32_16x16x32_bf16(bfr[j], af[i], acc[i][j], 0, 0, 0);
            } else {
#pragma unroll
                for (int i = 0; i < 4; ++i)
#pragma unroll
                    for (int j = 0; j < 4; ++j)
                        acc[i][j] = __builtin_amdgcn_mfma_f32_16x16x32_bf16(af[i], bfr[j], acc[i][j], 0, 0, 0);
            }
        }
    }

    // 0.125 * log2(e): scores later exponentiate via exp2
    const float scale = (z == 0) ? 0.18033688011112042f : 1.0f;
#pragma unroll
    for (int i = 0; i < 4; ++i) {
#pragma unroll
        for (int j = 0; j < 4; ++j) {
#pragma unroll
            for (int r = 0; r < 4; ++r) {
                float v = acc[i][j][r];
                if (z == 2) {
                    int n = colB0 + wc + j * 16 + quad * 4 + r;  // feature (h*64+d)
                    int m = rowA0 + wr + i * 16 + c;             // token (b*2048+s)
                    int b = m >> 11, s = m & 2047, h = n >> 6, d = n & 63;
                    Out[((((b << 4) | h) << 6) + d) * 2048 + s] = f2bf(v);
                } else {
                    int m = rowA0 + wr + i * 16 + quad * 4 + r;  // token
                    int n = colB0 + wc + j * 16 + c;             // feature
                    int b = m >> 11, s = m & 2047, h = n >> 6, d = n & 63;
                    Out[((((b << 4) | h) * 2048 + s) << 6) + d] = f2bf(v * scale);
                }
            }
        }
    }
}

// ---------------- output projection GEMM (fp32 out, async-LDS, swizzled) ----------------
// Tile 64(M) x 128(N). 1-D grid 512: blk = yb + 64*xb => blk%8 == yb%8, so the 8
// x-tiles sharing A-rows cluster per XCD (A 1MB + W 2MB working set, L2-resident).
__global__ __launch_bounds__(256, 2) void out_gemm(const u16* __restrict__ A,
                                                   const u16* __restrict__ W,
                                                   float* __restrict__ Out) {
    constexpr int K = 1024;
    __shared__ __align__(16) u16 As[64 * 64];   // 8 KB
    __shared__ __align__(16) u16 Bs[128 * 64];  // 16 KB
    const int blk = blockIdx.x;
    const int yb = blk & 63;
    const int xb = blk >> 6;
    const int t = threadIdx.x;
    const int lane = t & 63, wave = t >> 6;
    const int quad = lane >> 4, c = lane & 15, cx = c & 7;
    const int wr = (wave >> 1) * 32, wc = (wave & 1) * 64;
    const int rowA0 = yb * 64;
    const int colB0 = xb * 128;

    const int l3 = lane >> 3, l7 = lane & 7;
    const int chs = (l7 ^ l3) << 3;
    const u16* gA[2];
    const u16* gB[4];
    u16* lA[2];
    u16* lB[4];
#pragma unroll
    for (int i = 0; i < 2; ++i) {
        int row = wave * 16 + i * 8 + l3;
        gA[i] = A + (size_t)(rowA0 + row) * K + chs;
        lA[i] = As + (wave * 128 + i * 64) * 8;
    }
#pragma unroll
    for (int i = 0; i < 4; ++i) {
        int row = wave * 32 + i * 8 + l3;
        gB[i] = W + (size_t)(colB0 + row) * K + chs;
        lB[i] = Bs + (wave * 256 + i * 64) * 8;
    }

    const f32x4 zero4 = {0.f, 0.f, 0.f, 0.f};
    f32x4 acc[2][4];
#pragma unroll
    for (int i = 0; i < 2; ++i)
#pragma unroll
        for (int j = 0; j < 4; ++j) acc[i][j] = zero4;

    for (int kt = 0; kt < K; kt += 64) {
        __syncthreads();
#pragma unroll
        for (int i = 0; i < 2; ++i) gload16(gA[i] + kt, lA[i]);
#pragma unroll
        for (int i = 0; i < 4; ++i) gload16(gB[i] + kt, lB[i]);
        __syncthreads();
#pragma unroll
        for (int ks = 0; ks < 2; ++ks) {
            const int co = ((ks * 4 + quad) ^ cx) << 3;
            bf16x8 af[2], bfr[4];
#pragma unroll
            for (int i = 0; i < 2; ++i)
                af[i] = *(const bf16x8*)(As + (wr + i * 16 + c) * 64 + co);
#pragma unroll
            for (int j = 0; j < 4; ++j)
                bfr[j] = *(const bf16x8*)(Bs + (wc + j * 16 + c) * 64 + co);
#pragma unroll
            for (int i = 0; i < 2; ++i)
#pragma unroll
                for (int j = 0; j < 4; ++j)
                    acc[i][j] = __builtin_amdgcn_mfma_f32_16x16x32_bf16(af[i], bfr[j], acc[i][j], 0, 0, 0);
        }
    }
#pragma unroll
    for (int i = 0; i < 2; ++i)
#pragma unroll
        for (int j = 0; j < 4; ++j)
#pragma unroll
            for (int r = 0; r < 4; ++r) {
                int m = rowA0 + wr + i * 16 + quad * 4 + r;
                int n = colB0 + wc + j * 16 + c;
                Out[(m << 10) + n] = acc[i][j][r];
            }
}

// ---------------- flash attention v6: XCD-local heads + MFMA row-sums ----------------
// r5 structure (double-buffered KV via global_load_lds, per-wave P with lgkm fence),
// plus: (a) 1-D grid 512 with bh = (blk%8)*4 + ((blk>>3)&3), qtile = blk>>5 — the 16
// q-tiles of 4 heads land on one XCD => 2 MB KV working set, L2-resident prefetches;
// (b) softmax denominator accumulated by MFMA against an all-ones B fragment — kills
// 32 VALU adds/iter and the epilogue shuffles (result is register-aligned with O).
__global__ __launch_bounds__(256, 2) void flash_attn(const u16* __restrict__ Qp,
                                                     const u16* __restrict__ Kp,
                                                     const u16* __restrict__ Vt,
                                                     u16* __restrict__ Ob) {
    constexpr int S = 2048;
    const int blk = blockIdx.x;
    const int j = blk & 31;
    const int bh = ((j & 7) << 2) | (j >> 3);
    const int b = bh >> 4, h = bh & 15;
    const int t = threadIdx.x, wave = t >> 6, lane = t & 63;
    const int quad = lane >> 4, c = lane & 15, cx = c & 7;
    const int qw = (blk >> 5) * 128 + wave * 32;
    const u16* Qb = Qp + (bh * S + qw) * 64;
    const u16* Kb = Kp + (bh * S) * 64;
    const u16* Vb = Vt + bh * 64 * S;

    __shared__ __align__(16) u16 Ks[2][64 * 64];  // [key][dim], swizzled chunks
    __shared__ __align__(16) u16 Vs[2][64 * 64];  // [dim][key], swizzled chunks
    __shared__ __align__(16) u16 Ps[4][32 * 64];  // per-wave P [q][key], swizzled
    u16* Pw = &Ps[wave][0];

    // Q fragments (B-operand): lane c holds Q[q=qt*16+c][dim=hf*32+quad*8+j]
    bf16x8 qf[2][2];
#pragma unroll
    for (int qt = 0; qt < 2; ++qt)
#pragma unroll
        for (int hf = 0; hf < 2; ++hf)
            qf[qt][hf] = *(const bf16x8*)(Qb + (qt * 16 + c) * 64 + hf * 32 + quad * 8);

    // all-ones bf16 B fragment for denominator MFMAs
    u16x8 ou;
#pragma unroll
    for (int i = 0; i < 8; ++i) ou[i] = 0x3F80;
    const bf16x8 onesf = __builtin_bit_cast(bf16x8, ou);

    // staging: wave w instr i covers physical chunks [w*128+i*64, +64)
    const int l3 = lane >> 3, l7 = lane & 7;
    const int chs = (l7 ^ l3) << 3;
    const u16* gK[2];
    const u16* gV[2];
    int lbase[2];
#pragma unroll
    for (int i = 0; i < 2; ++i) {
        int row = wave * 16 + i * 8 + l3;
        gK[i] = Kb + row * 64 + chs;    // += kv*64 per tile
        gV[i] = Vb + row * 2048 + chs;  // += kv per tile
        lbase[i] = (wave * 128 + i * 64) * 8;
    }
    // preload tile 0
#pragma unroll
    for (int i = 0; i < 2; ++i) {
        gload16(gK[i], &Ks[0][lbase[i]]);
        gload16(gV[i], &Vs[0][lbase[i]]);
    }
    __syncthreads();

    const f32x4 zero4 = {0.f, 0.f, 0.f, 0.f};
    f32x4 o[2][4];
    f32x4 ol[2];  // denominator: D[q][*] = row-sum of P (register-aligned with o)
#pragma unroll
    for (int qt = 0; qt < 2; ++qt) {
        ol[qt] = zero4;
#pragma unroll
        for (int t2 = 0; t2 < 4; ++t2) o[qt][t2] = zero4;
    }

    const int co0 = (quad ^ cx) << 3, co1 = ((4 + quad) ^ cx) << 3;

    for (int it = 0; it < S / 64; ++it) {
        const int cur = it & 1;
        // prefetch next tile into the other buffer (completes at this iter's barrier)
        if (it + 1 < S / 64) {
#pragma unroll
            for (int i = 0; i < 2; ++i) {
                gload16(gK[i] + (it + 1) * 4096, &Ks[cur ^ 1][lbase[i]]);
                gload16(gV[i] + (it + 1) * 64, &Vs[cur ^ 1][lbase[i]]);
            }
        }
        const u16* Kc = &Ks[cur][0];
        const u16* Vc = &Vs[cur][0];
        // ---- transposed scores: Sc^T[key][q] = K_tile * Q^T ----
        f32x4 sc[4][2];
#pragma unroll
        for (int kt = 0; kt < 4; ++kt) {
            const int krow = (kt * 16 + c) * 64;
            bf16x8 kf0 = *(const bf16x8*)(Kc + krow + co0);
            bf16x8 kf1 = *(const bf16x8*)(Kc + krow + co1);
#pragma unroll
            for (int qt = 0; qt < 2; ++qt) {
                f32x4 zz = zero4;
                zz = __builtin_amdgcn_mfma_f32_16x16x32_bf16(kf0, qf[qt][0], zz, 0, 0, 0);
                zz = __builtin_amdgcn_mfma_f32_16x16x32_bf16(kf1, qf[qt][1], zz, 0, 0, 0);
                sc[kt][qt] = zz;
            }
        }
        // ---- exp2 + pack + swizzled P write (per-wave LDS, no barrier) ----
        // lane holds keys kt*16+quad*4+r for q = qt*16+c
#pragma unroll
        for (int kt = 0; kt < 4; ++kt) {
            const int pchunk = ((kt * 2 + (quad >> 1)) ^ cx) << 3;
#pragma unroll
            for (int qt = 0; qt < 2; ++qt) {
                float p0 = EXP2(sc[kt][qt][0]);
                float p1 = EXP2(sc[kt][qt][1]);
                float p2 = EXP2(sc[kt][qt][2]);
                float p3 = EXP2(sc[kt][qt][3]);
                uint2 pk;
                pk.x = pack2_rhu(p0, p1);
                pk.y = pack2_rhu(p2, p3);
                *(uint2*)(Pw + (qt * 16 + c) * 64 + pchunk + (quad & 1) * 4) = pk;
            }
        }
        __asm__ __volatile__("s_waitcnt lgkmcnt(0)" ::: "memory");
        // ---- P fragments (A-operand) + O += P*V, l += P*ones ----
        bf16x8 pf[2][2];
#pragma unroll
        for (int qt = 0; qt < 2; ++qt) {
            pf[qt][0] = *(const bf16x8*)(Pw + (qt * 16 + c) * 64 + co0);
            pf[qt][1] = *(const bf16x8*)(Pw + (qt * 16 + c) * 64 + co1);
        }
#pragma unroll
        for (int qt = 0; qt < 2; ++qt) {
            ol[qt] = __builtin_amdgcn_mfma_f32_16x16x32_bf16(pf[qt][0], onesf, ol[qt], 0, 0, 0);
            ol[qt] = __builtin_amdgcn_mfma_f32_16x16x32_bf16(pf[qt][1], onesf, ol[qt], 0, 0, 0);
        }
#pragma unroll
        for (int t2 = 0; t2 < 4; ++t2) {
            const int vrow = (t2 * 16 + c) * 64;
            bf16x8 vf0 = *(const bf16x8*)(Vc + vrow + co0);
            bf16x8 vf1 = *(const bf16x8*)(Vc + vrow + co1);
#pragma unroll
            for (int qt = 0; qt < 2; ++qt) {
                o[qt][t2] = __builtin_amdgcn_mfma_f32_16x16x32_bf16(pf[qt][0], vf0, o[qt][t2], 0, 0, 0);
                o[qt][t2] = __builtin_amdgcn_mfma_f32_16x16x32_bf16(pf[qt][1], vf1, o[qt][t2], 0, 0, 0);
            }
        }
        __syncthreads();  // buffer lifecycle + drains prefetch vmcnt
    }
    // ---- epilogue: normalize and store [B,S,H,D]; ol[qt][r] is the row-sum for
    // row quad*4+r — exactly the row o[qt][..][r] holds. No shuffles needed. ----
#pragma unroll
    for (int qt = 0; qt < 2; ++qt)
#pragma unroll
        for (int r = 0; r < 4; ++r) {
            float inv = 1.f / ol[qt][r];
            int row = qw + qt * 16 + quad * 4 + r;
            int base = ((b * S + row) * 16 + h) * 64;
#pragma unroll
            for (int t2 = 0; t2 < 4; ++t2)
                Ob[base + t2 * 16 + c] = f2bf(o[qt][t2][r] * inv);
        }
}

extern "C" void kernel_launch(void* const* d_in, const int* in_sizes, int n_in,
                              void* d_out, int out_size, void* d_ws, size_t ws_size,
                              hipStream_t stream) {
    const float* q  = (const float*)d_in[0];
    const float* k  = (const float*)d_in[1];
    const float* v  = (const float*)d_in[2];
    const float* wq = (const float*)d_in[3];
    const float* wk = (const float*)d_in[4];
    const float* wv = (const float*)d_in[5];
    const float* wo = (const float*)d_in[6];

    u16* ws = (u16*)d_ws;
    u16* qb  = ws;              // 4194304 elems
    u16* kb  = ws + 4194304;
    u16* vb  = ws + 8388608;
    u16* wqb = ws + 12582912;   // 1048576 elems each
    u16* wkb = ws + 13631488;
    u16* wvb = ws + 14680064;
    u16* wob = ws + 15728640;
    u16* Qp  = ws + 16777216;   // [B,H,S,D]
    u16* Kp  = ws + 20971520;   // [B,H,S,D]
    u16* Vtp = ws + 25165824;   // [B,H,D,S]
    u16* Obf = ws + 29360128;   // [B,S,H,D]

    cast_all<<<16384, 256, 0, stream>>>(q, k, v, wq, wk, wv, wo, ws);

    // fused QKV projections: 1-D grid 768, XCD-grouped by (z, y)
    qkv_gemm<<<768, 256, 0, stream>>>(qb, kb, vb, wqb, wkb, wvb, Qp, Kp, Vtp);

    // flash attention: 1-D grid 512, XCD-grouped heads
    flash_attn<<<512, 256, 0, stream>>>(Qp, Kp, Vtp, Obf);

    // output projection: 1-D grid 512, XCD-grouped by y
    out_gemm<<<512, 256, 0, stream>>>(Obf, wob, (float*)d_out);
}